// Round 3
// baseline (770.752 us; speedup 1.0000x reference)
//
#include <hip/hip_runtime.h>

// SSIM loss, streaming-row kernel. Inputs: 2x (32,3,512,512) fp32; out scalar.
// Block = 256 threads x full 512-col width, 2 cols/thread, 64-row band.
// Raw x/y rows staged in a 4-slot LDS ring (sole LDS use); horizontal 11-tap
// blur per lane from 12 LDS values; vertical blur via 11 in-flight register
// accumulators per map (slot indices compile-time via 11-phase unroll; the
// d==0 tap ASSIGNS its slot, so no init/reset and no cross-band contamination).
// One output row completes per phase. 1 barrier/phase.

#define IMG 512
#define OUT_DIM 502    // 512 - 10 (VALID conv twice)
#define WIN 11
#define BH 64          // output rows per band; 8 bands x 96 planes = 768 blocks
#define NPLANES 96
#define LW 524         // 512 + 12 zero pad (right halo for lanes >= 251)

__global__ __launch_bounds__(256, 3) void ssim_stream(const float* __restrict__ X,
                                                      const float* __restrict__ Y,
                                                      float* __restrict__ planeSums) {
    // Gaussian(11, sigma=1.5), normalized; matches numpy fp32 (absmax 0.0 in r1/r2).
    constexpr float G[WIN] = {0.00102838f, 0.00759875f, 0.03600077f, 0.10936071f,
                              0.21300553f, 0.26601172f, 0.21300553f, 0.10936071f,
                              0.03600077f, 0.00759875f, 0.00102838f};

    __shared__ float xs[4][LW];
    __shared__ float ys[4][LW];

    const int tid = threadIdx.x;
    const int band = blockIdx.x;
    const int plane = blockIdx.y;
    const int r0 = band * BH;
    const size_t pbase = (size_t)plane * IMG * IMG;
    const float* Xp = X + pbase;
    const float* Yp = Y + pbase;
    const int c0 = tid << 1;                       // this lane's 2 output cols
    const int validEnd = min(r0 + BH, OUT_DIM);

    // Zero the right-halo pad once (LDS is re-poisoned before every launch).
    if (tid < 48) {
        const int slot = tid / 12, p = tid - slot * 12;
        xs[slot][IMG + p] = 0.f;
        ys[slot][IMG + p] = 0.f;
    }
    // Prologue: rows r0, r0+1 into ring slots 0,1.
    #pragma unroll
    for (int i = 0; i < 2; ++i) {
        const float2 xv = *(const float2*)(Xp + (r0 + i) * IMG + c0);
        const float2 yv = *(const float2*)(Yp + (r0 + i) * IMG + c0);
        *(float2*)&xs[i][c0] = xv;
        *(float2*)&ys[i][c0] = yv;
    }
    __syncthreads();

    float a[5][2][WIN];   // vertical accumulators; d==0 assigns, so no init
    float local = 0.f;

    for (int base = 0; base < 77; base += WIN) {   // 7 bodies x 11 phases
        #pragma unroll
        for (int ph = 0; ph < WIN; ++ph) {
            const int p = base + ph;               // phase (row offset in band)
            const int r = r0 + p;                  // input row this phase

            // Prefetch row r+2 early; its vmcnt drains only at the post-barrier write.
            float2 px = make_float2(0.f, 0.f), py = make_float2(0.f, 0.f);
            const int rp = r + 2;
            if (rp < IMG) {
                px = *(const float2*)(Xp + rp * IMG + c0);
                py = *(const float2*)(Yp + rp * IMG + c0);
            }

            // Horizontal 11-tap blur of the 5 product maps for 2 columns.
            float h[5][2];
            if (r < IMG) {                          // uniform; false only in last band's tail
                float xr[12], yr[12];
                const float* xrow = xs[p & 3];
                const float* yrow = ys[p & 3];
                #pragma unroll
                for (int i = 0; i < 6; ++i) {       // 6+6 ds_read_b64, 2-way bank alias (free)
                    *(float2*)&xr[2 * i] = *(const float2*)&xrow[c0 + 2 * i];
                    *(float2*)&yr[2 * i] = *(const float2*)&yrow[c0 + 2 * i];
                }
                #pragma unroll
                for (int c = 0; c < 2; ++c) {
                    float h0 = 0.f, h1 = 0.f, h2 = 0.f, h3 = 0.f, h4 = 0.f;
                    #pragma unroll
                    for (int k = 0; k < WIN; ++k) {
                        const float w = G[k];
                        const float xv = xr[k + c], yv = yr[k + c];
                        const float wx = w * xv, wy = w * yv;
                        h0 += wx;
                        h1 += wy;
                        h2 = fmaf(wx, xv, h2);
                        h3 = fmaf(wy, yv, h3);
                        h4 = fmaf(wx, yv, h4);
                    }
                    h[0][c] = h0; h[1][c] = h1; h[2][c] = h2; h[3][c] = h3; h[4][c] = h4;
                }
            } else {
                #pragma unroll
                for (int m = 0; m < 5; ++m) { h[m][0] = 0.f; h[m][1] = 0.f; }
            }

            // Vertical accumulation: row r contributes weight G[d] to output r-d.
            #pragma unroll
            for (int d = 0; d < WIN; ++d) {
                const int s = (ph - d + 22) % WIN;  // compile-time slot
                const float w = G[d];
                #pragma unroll
                for (int m = 0; m < 5; ++m) {
                    #pragma unroll
                    for (int c = 0; c < 2; ++c) {
                        if (d == 0) a[m][c][s] = w * h[m][c];          // assign: kills stale state
                        else        a[m][c][s] = fmaf(w, h[m][c], a[m][c][s]);
                    }
                }
            }

            // Output row o = r-10 completed this phase.
            const int o = r0 + p - 10;
            if (p >= 10 && o < validEnd) {          // uniform branch
                const int se = (ph + 1) % WIN;      // == (p-10) % 11
                const float C1 = 0.0001f, C2 = 0.0009f;
                #pragma unroll
                for (int c = 0; c < 2; ++c) {
                    if (c0 + c < OUT_DIM) {
                        const float m1 = a[0][c][se], m2 = a[1][c][se];
                        const float m1sq = m1 * m1, m2sq = m2 * m2, m12 = m1 * m2;
                        const float s1  = a[2][c][se] - m1sq;
                        const float s2  = a[3][c][se] - m2sq;
                        const float s12 = a[4][c][se] - m12;
                        const float num = (2.f * m12 + C1) * (2.f * s12 + C2);
                        const float den = (m1sq + m2sq + C1) * (s1 + s2 + C2);
                        local += num * __builtin_amdgcn_rcpf(den);
                    }
                }
            }

            // Ring rotate: all waves done reading slot p&3; publish row r+2.
            __syncthreads();
            *(float2*)&xs[(p + 2) & 3][c0] = px;
            *(float2*)&ys[(p + 2) & 3][c0] = py;
        }
    }

    // Block reduction -> one atomic per block (8 blocks/plane).
    #pragma unroll
    for (int off = 32; off > 0; off >>= 1)
        local += __shfl_down(local, off, 64);
    __shared__ float red[4];
    if ((tid & 63) == 0) red[tid >> 6] = local;
    __syncthreads();
    if (tid == 0)
        atomicAdd(&planeSums[plane], (red[0] + red[1]) + (red[2] + red[3]));
}

__global__ __launch_bounds__(128) void ssim_finalize(const float* __restrict__ planeSums,
                                                     float* __restrict__ out) {
    const int tid = threadIdx.x;
    float v = 0.f;
    if (tid < NPLANES) {
        const float m = planeSums[tid] * (1.0f / (float)(OUT_DIM * OUT_DIM));
        v = fmaxf(m, 0.f);   // nonnegative_ssim relu
    }
    #pragma unroll
    for (int off = 32; off > 0; off >>= 1)
        v += __shfl_down(v, off, 64);
    __shared__ float red[2];
    if ((tid & 63) == 0) red[tid >> 6] = v;
    __syncthreads();
    if (tid == 0) out[0] = 1.0f - (red[0] + red[1]) * (1.0f / (float)NPLANES);
}

extern "C" void kernel_launch(void* const* d_in, const int* in_sizes, int n_in,
                              void* d_out, int out_size, void* d_ws, size_t ws_size,
                              hipStream_t stream) {
    const float* X = (const float*)d_in[0];   // predictions
    const float* Y = (const float*)d_in[1];   // labels
    float* out = (float*)d_out;
    float* ws  = (float*)d_ws;                // 96 per-plane sums

    hipMemsetAsync(ws, 0, NPLANES * sizeof(float), stream);

    dim3 grid(IMG / BH, NPLANES);             // 8 x 96 = 768 blocks = 3/CU
    ssim_stream<<<grid, 256, 0, stream>>>(X, Y, ws);
    ssim_finalize<<<1, 128, 0, stream>>>(ws, out);
}

// Round 4
// 346.487 us; speedup vs baseline: 2.2245x; 2.2245x over previous
//
#include <hip/hip_runtime.h>

// SSIM loss, streaming-row kernel, no LDS, no barriers.
// Inputs: 2x (32,3,512,512) fp32; out scalar. Block = 256 threads x full
// 512-col width, 2 cols/thread, 32-row band (grid 16x96 = 1536 blocks =
// 3 perfectly-packed rounds at 2 blocks/CU).
// Each phase: thread loads its 12-col x/y window from global (6+6 aligned
// float2; halo overlap -> L1), h-blurs the 5 product maps, feeds 11
// in-flight vertical accumulators per map held in REGISTERS.
// r3 lesson: dynamic-looking array indices sent a[5][2][11] to scratch
// (543 MB WRITE_SIZE). Fix: template<int PH> phases -> every index is a
// literal constant -> guaranteed SROA; launch_bounds(256,2) caps at 256
// VGPRs so the ~195-reg working set cannot spill.

#define IMG 512
#define OUT_DIM 502    // 512 - 10 (VALID conv twice)
#define WIN 11
#define BH 32          // output rows per band
#define NPHASE (BH + WIN - 1)   // 42
#define NPLANES 96

template<int PH>
__device__ __forceinline__ void phase_step(int base, int r0, int c0, int cbase,
                                           const float* __restrict__ Xp,
                                           const float* __restrict__ Yp,
                                           float (&a)[5][2][WIN], float& local) {
    // Gaussian(11, sigma=1.5), normalized; matches numpy fp32 (absmax 0.0 r1/r2).
    constexpr float G[WIN] = {0.00102838f, 0.00759875f, 0.03600077f, 0.10936071f,
                              0.21300553f, 0.26601172f, 0.21300553f, 0.10936071f,
                              0.03600077f, 0.00759875f, 0.00102838f};
    const int p = base + PH;
    if (p >= NPHASE) return;                  // uniform; only last outer iter
    const int rr = min(r0 + p, IMG - 1);      // clamped rows feed only discarded outputs
    const float* px = Xp + rr * IMG + cbase;
    const float* py = Yp + rr * IMG + cbase;

    float x[12], y[12];
    #pragma unroll
    for (int i = 0; i < 6; ++i) {             // 12 aligned float2 loads, L1-served halo
        const float2 xv = *(const float2*)(px + 2 * i);
        const float2 yv = *(const float2*)(py + 2 * i);
        x[2 * i] = xv.x; x[2 * i + 1] = xv.y;
        y[2 * i] = yv.x; y[2 * i + 1] = yv.y;
    }
    float xx[12], yy[12], xy[12];             // products shared by both cols
    #pragma unroll
    for (int i = 0; i < 12; ++i) {
        xx[i] = x[i] * x[i];
        yy[i] = y[i] * y[i];
        xy[i] = x[i] * y[i];
    }

    float h[5][2];
    #pragma unroll
    for (int c = 0; c < 2; ++c) {
        float h0 = 0.f, h1 = 0.f, h2 = 0.f, h3 = 0.f, h4 = 0.f;
        #pragma unroll
        for (int k = 0; k < WIN; ++k) {
            h0 = fmaf(G[k], x[k + c], h0);
            h1 = fmaf(G[k], y[k + c], h1);
            h2 = fmaf(G[k], xx[k + c], h2);
            h3 = fmaf(G[k], yy[k + c], h3);
            h4 = fmaf(G[k], xy[k + c], h4);
        }
        h[0][c] = h0; h[1][c] = h1; h[2][c] = h2; h[3][c] = h3; h[4][c] = h4;
    }

    // Row r contributes weight G[d] to output row r-d; slot (p-d) mod 11.
    // d==0 ASSIGNS its slot (freed by last phase's emit) -> no init/reset.
    #pragma unroll
    for (int d = 0; d < WIN; ++d) {
        constexpr int ds = PH;                // keep PH constexpr-visible
        const int s = (ds - d + 2 * WIN) % WIN;   // literal constant after unroll
        const float w = G[d];
        #pragma unroll
        for (int m = 0; m < 5; ++m)
            #pragma unroll
            for (int c = 0; c < 2; ++c)
                a[m][c][s] = (d == 0) ? (w * h[m][c]) : fmaf(w, h[m][c], a[m][c][s]);
    }

    // Output row o = r-10 completed this phase; its slot is (PH+1)%11.
    if (p >= WIN - 1) {
        const int o = r0 + p - (WIN - 1);
        if (o < OUT_DIM && c0 < OUT_DIM) {    // c0 even: c0<502 covers both cols
            constexpr int se = (PH + 1) % WIN;
            const float C1 = 0.0001f, C2 = 0.0009f;
            #pragma unroll
            for (int c = 0; c < 2; ++c) {
                const float m1 = a[0][c][se], m2 = a[1][c][se];
                const float m1sq = m1 * m1, m2sq = m2 * m2, m12 = m1 * m2;
                const float s1  = a[2][c][se] - m1sq;
                const float s2  = a[3][c][se] - m2sq;
                const float s12 = a[4][c][se] - m12;
                const float num = (2.f * m12 + C1) * (2.f * s12 + C2);
                const float den = (m1sq + m2sq + C1) * (s1 + s2 + C2);
                local += num * __builtin_amdgcn_rcpf(den);
            }
        }
    }
}

__global__ __launch_bounds__(256, 2) void ssim_stream(const float* __restrict__ X,
                                                      const float* __restrict__ Y,
                                                      float* __restrict__ planeSums) {
    const int tid = threadIdx.x;
    const int r0 = blockIdx.x * BH;
    const int plane = blockIdx.y;
    const size_t pbase = (size_t)plane * IMG * IMG;
    const float* Xp = X + pbase;
    const float* Yp = Y + pbase;
    const int c0 = tid << 1;                  // this lane's 2 output cols
    const int cbase = min(c0, IMG - 12);      // clamp: loads stay in-bounds;
                                              // clamped lanes never emit

    float a[5][2][WIN];                       // 110 regs once SROA'd
    float local = 0.f;

    for (int base = 0; base < 44; base += WIN) {  // 4 x 11 phases, guard trims to 42
        phase_step<0>(base, r0, c0, cbase, Xp, Yp, a, local);
        phase_step<1>(base, r0, c0, cbase, Xp, Yp, a, local);
        phase_step<2>(base, r0, c0, cbase, Xp, Yp, a, local);
        phase_step<3>(base, r0, c0, cbase, Xp, Yp, a, local);
        phase_step<4>(base, r0, c0, cbase, Xp, Yp, a, local);
        phase_step<5>(base, r0, c0, cbase, Xp, Yp, a, local);
        phase_step<6>(base, r0, c0, cbase, Xp, Yp, a, local);
        phase_step<7>(base, r0, c0, cbase, Xp, Yp, a, local);
        phase_step<8>(base, r0, c0, cbase, Xp, Yp, a, local);
        phase_step<9>(base, r0, c0, cbase, Xp, Yp, a, local);
        phase_step<10>(base, r0, c0, cbase, Xp, Yp, a, local);
    }

    // Block reduction -> one atomic per block (16 blocks/plane).
    #pragma unroll
    for (int off = 32; off > 0; off >>= 1)
        local += __shfl_down(local, off, 64);
    __shared__ float red[4];
    if ((tid & 63) == 0) red[tid >> 6] = local;
    __syncthreads();
    if (tid == 0)
        atomicAdd(&planeSums[plane], (red[0] + red[1]) + (red[2] + red[3]));
}

__global__ __launch_bounds__(128) void ssim_finalize(const float* __restrict__ planeSums,
                                                     float* __restrict__ out) {
    const int tid = threadIdx.x;
    float v = 0.f;
    if (tid < NPLANES) {
        const float m = planeSums[tid] * (1.0f / (float)(OUT_DIM * OUT_DIM));
        v = fmaxf(m, 0.f);   // nonnegative_ssim relu
    }
    #pragma unroll
    for (int off = 32; off > 0; off >>= 1)
        v += __shfl_down(v, off, 64);
    __shared__ float red[2];
    if ((tid & 63) == 0) red[tid >> 6] = v;
    __syncthreads();
    if (tid == 0) out[0] = 1.0f - (red[0] + red[1]) * (1.0f / (float)NPLANES);
}

extern "C" void kernel_launch(void* const* d_in, const int* in_sizes, int n_in,
                              void* d_out, int out_size, void* d_ws, size_t ws_size,
                              hipStream_t stream) {
    const float* X = (const float*)d_in[0];   // predictions
    const float* Y = (const float*)d_in[1];   // labels
    float* out = (float*)d_out;
    float* ws  = (float*)d_ws;                // 96 per-plane sums

    hipMemsetAsync(ws, 0, NPLANES * sizeof(float), stream);

    dim3 grid((OUT_DIM + BH - 1) / BH, NPLANES);   // 16 x 96 = 1536 blocks
    ssim_stream<<<grid, 256, 0, stream>>>(X, Y, ws);
    ssim_finalize<<<1, 128, 0, stream>>>(ws, out);
}